// Round 3
// baseline (5262.106 us; speedup 1.0000x reference)
//
#include <hip/hip_runtime.h>
#include <math.h>

// Residual VQ, 4 stages, N=16384 rows, D=512, K=4096.
// Round 3: bit-exact replication of a NUMPY FLOAT32 reference:
//   dist = fl32( fl32( rsq - fl32(2*dot) ) + cbsq ),  argmin first-index
//   rsq/cbsq: numpy pairwise sum, AVX512 base-case tree
//   dot: sequential fp32 FMA chain over d=0..511
//   residual: r_new = fl(r - fl(r + fl(q - r)))

namespace {
constexpr int N_ROWS     = 16384;
constexpr int DIM        = 512;
constexpr int K_CODES    = 4096;
constexpr int NUM_STAGES = 4;

constexpr int TM = 64;
constexpr int TK = 64;
constexpr int DC = 32;
constexpr int KTILES = K_CODES / TK;   // 64
constexpr int STR = DC + 5;            // LDS row stride 37: breaks pow2 bank aliasing

// d_out layout (all read back as float32):
constexpr size_t Q_OFF    = 0;
constexpr size_t IDX_OFF  = (size_t)N_ROWS * DIM;                  // 8388608
constexpr size_t LOSS_OFF = IDX_OFF + (size_t)N_ROWS * NUM_STAGES; // 8454144

// ws layout (bytes):
constexpr size_t RES_OFF  = 0;                                   // 32 MB
constexpr size_t CBSQ_OFF = (size_t)N_ROWS * DIM * 4;            // +16 KB
constexpr size_t RSQ_OFF  = CBSQ_OFF + (size_t)K_CODES * 4;      // +64 KB
constexpr size_t PART_OFF = RSQ_OFF + (size_t)N_ROWS * 4;        // +8 MB

struct Partial { float val; int idx; };
} // namespace

// numpy pairwise sum-of-squares of a 512-float row, AVX512 base-case order.
// Valid result on lane 0 of each wave.
__device__ __forceinline__ float rowsq_pairwise(const float* __restrict__ row,
                                                int lane) {
#pragma clang fp contract(off)
    float P[4];
#pragma unroll
    for (int b = 0; b < 4; ++b) {
        float xa = row[b * 128 + lane];
        float xb = row[b * 128 + 64 + lane];
        float sa = xa * xa;            // fl32 squares (terms of the reduction)
        float sb = xb * xb;
        float R  = sa + sb;            // r_j[l] = sq[16j+l] + sq[64+16j+l]
        float t  = R + __shfl_down(R, 16, 64);   // r0+r1 | r2+r3
        float u  = t + __shfl_down(t, 32, 64);   // (r0+r1)+(r2+r3), lanes 0..15
        float a  = u + __shfl_down(u, 8, 64);    // _mm512_reduce_add_ps tree
        float c  = a + __shfl_down(a, 4, 64);
        float d  = c + __shfl_down(c, 2, 64);
        P[b]     = d + __shfl_down(d, 1, 64);
    }
    float s01 = P[0] + P[1];
    float s23 = P[2] + P[3];
    return s01 + s23;
}

__global__ __launch_bounds__(64)
void cbsq_kernel(const float* __restrict__ cb, float* __restrict__ cb_sq,
                 float* __restrict__ loss) {
    int k = blockIdx.x;
    int lane = threadIdx.x;
    float s = rowsq_pairwise(cb + (size_t)k * DIM, lane);
    if (lane == 0) cb_sq[k] = s;
    if (k == 0 && lane == 0) *loss = 0.0f;
}

__global__ __launch_bounds__(256)
void rsq_kernel(const float* __restrict__ res, float* __restrict__ rsq) {
    int lane = threadIdx.x & 63;
    int sub  = threadIdx.x >> 6;
    int row  = blockIdx.x * 4 + sub;
    float s = rowsq_pairwise(res + (size_t)row * DIM, lane);
    if (lane == 0) rsq[row] = s;
}

// Tiled fp32 distance (sequential-d FMA chain) + per-(row,ktile) argmin.
__global__ __launch_bounds__(256)
void dist_argmin_kernel(const float* __restrict__ res,
                        const float* __restrict__ cb,
                        const float* __restrict__ cb_sq,
                        const float* __restrict__ rsq,
                        Partial* __restrict__ part) {
    const int mb = blockIdx.x;
    const int kb = blockIdx.y;

    __shared__ float As[TM][STR];
    __shared__ float Bs[TK][STR];
    __shared__ float bval[TM][16];
    __shared__ int   bidx[TM][16];

    const int t  = threadIdx.x;
    const int tx = t & 15;
    const int ty = t >> 4;

    float acc[4][4];
#pragma unroll
    for (int i = 0; i < 4; ++i)
#pragma unroll
        for (int j = 0; j < 4; ++j) acc[i][j] = 0.0f;

    const float* aBase = res + (size_t)mb * TM * DIM;
    const float* bBase = cb  + (size_t)kb * TK * DIM;

    for (int d0 = 0; d0 < DIM; d0 += DC) {
        // Stage A[64][32], B[64][32]: 512 float4 each; scalar LDS writes
        // (stride 37 is not 16B-aligned).
#pragma unroll
        for (int l = 0; l < 2; ++l) {
            int f   = t + l * 256;
            int row = f >> 3;
            int c4  = (f & 7) * 4;
            float4 va = *reinterpret_cast<const float4*>(aBase + (size_t)row * DIM + d0 + c4);
            As[row][c4 + 0] = va.x; As[row][c4 + 1] = va.y;
            As[row][c4 + 2] = va.z; As[row][c4 + 3] = va.w;
            float4 vb = *reinterpret_cast<const float4*>(bBase + (size_t)row * DIM + d0 + c4);
            Bs[row][c4 + 0] = vb.x; Bs[row][c4 + 1] = vb.y;
            Bs[row][c4 + 2] = vb.z; Bs[row][c4 + 3] = vb.w;
        }
        __syncthreads();

        // Sequential d ascending -> exact BLAS-style single-accumulator chain.
#pragma unroll
        for (int d = 0; d < DC; ++d) {
            float a[4], b[4];
#pragma unroll
            for (int i = 0; i < 4; ++i) a[i] = As[ty * 4 + i][d];
#pragma unroll
            for (int j = 0; j < 4; ++j) b[j] = Bs[tx * 4 + j][d];
#pragma unroll
            for (int i = 0; i < 4; ++i)
#pragma unroll
                for (int j = 0; j < 4; ++j)
                    acc[i][j] = fmaf(a[i], b[j], acc[i][j]);
        }
        __syncthreads();
    }

    // dist = fl32(fl32(rsq - fl32(2*dot)) + cbsq); argmin, first-index ties.
#pragma unroll
    for (int i = 0; i < 4; ++i) {
        float rsqv = rsq[mb * TM + ty * 4 + i];
        float bv = INFINITY; int bi = 0x7fffffff;
#pragma unroll
        for (int j = 0; j < 4; ++j) {
            int kglob = kb * TK + tx * 4 + j;
            float y;
            {
#pragma clang fp contract(off)
                float t2 = 2.0f * acc[i][j];
                float u  = rsqv - t2;
                y        = u + cb_sq[kglob];
            }
            if (y < bv || (y == bv && kglob < bi)) { bv = y; bi = kglob; }
        }
        bval[ty * 4 + i][tx] = bv;
        bidx[ty * 4 + i][tx] = bi;
    }
    __syncthreads();

    if (t < TM) {
        float bv = bval[t][0]; int bi = bidx[t][0];
#pragma unroll
        for (int x = 1; x < 16; ++x) {
            float v = bval[t][x]; int ix = bidx[t][x];
            if (v < bv || (v == bv && ix < bi)) { bv = v; bi = ix; }
        }
        Partial p; p.val = bv; p.idx = bi;
        part[(size_t)(mb * TM + t) * KTILES + kb] = p;
    }
}

// Reduce partials; write index (as float), exact fp32 residual/q_ste update.
__global__ __launch_bounds__(256)
void combine_kernel(float* __restrict__ res_out,
                    const float* __restrict__ res_in,
                    const float* __restrict__ cb,
                    const Partial* __restrict__ part,
                    float* __restrict__ qout,
                    float* __restrict__ idx_out,
                    int stage) {
#pragma clang fp contract(off)
    const int t    = threadIdx.x;
    const int lane = t & 63;
    const int sub  = t >> 6;
    const int row  = blockIdx.x * 4 + sub;

    Partial p = part[(size_t)row * KTILES + lane];
    float bv = p.val; int bi = p.idx;
#pragma unroll
    for (int off = 32; off > 0; off >>= 1) {
        float ov = __shfl_down(bv, off, 64);
        int   oi = __shfl_down(bi, off, 64);
        if (ov < bv || (ov == bv && oi < bi)) { bv = ov; bi = oi; }
    }
    bi = __shfl(bi, 0, 64);

    if (lane == 0) idx_out[(size_t)row * NUM_STAGES + stage] = (float)bi;

    const float* w   = cb + (size_t)bi * DIM;
    const float* rin = res_in + (size_t)row * DIM;
    float*       r   = res_out + (size_t)row * DIM;
    float*       q   = qout + (size_t)row * DIM;
#pragma unroll
    for (int i = 0; i < DIM / 64; ++i) {
        int d = lane + i * 64;
        float wv = w[d];
        float rv = rin[d];
        float tq    = wv - rv;     // fl(q - r)
        float q_ste = rv + tq;     // fl(r + (q - r))
        float rn    = rv - q_ste;  // fl(r - q_ste)
        r[d] = rn;
        if (stage == 0) q[d] = q_ste;
        else            q[d] = q[d] + q_ste;   // stage-order fp32 accumulation
    }
}

extern "C" void kernel_launch(void* const* d_in, const int* in_sizes, int n_in,
                              void* d_out, int out_size, void* d_ws, size_t ws_size,
                              hipStream_t stream) {
    const float* input = (const float*)d_in[0];
    const float* cb    = (const float*)d_in[1];

    float* out_f   = (float*)d_out;
    float* qout    = out_f + Q_OFF;
    float* idx_out = out_f + IDX_OFF;
    float* loss    = out_f + LOSS_OFF;

    char* ws = (char*)d_ws;
    float*   residual = (float*)(ws + RES_OFF);
    float*   cb_sq    = (float*)(ws + CBSQ_OFF);
    float*   rsq      = (float*)(ws + RSQ_OFF);
    Partial* part     = (Partial*)(ws + PART_OFF);

    cbsq_kernel<<<K_CODES, 64, 0, stream>>>(cb, cb_sq, loss);

    for (int s = 0; s < NUM_STAGES; ++s) {
        const float* rin = (s == 0) ? input : residual;
        rsq_kernel<<<N_ROWS / 4, 256, 0, stream>>>(rin, rsq);
        dist_argmin_kernel<<<dim3(N_ROWS / TM, KTILES), 256, 0, stream>>>(
            rin, cb, cb_sq, rsq, part);
        combine_kernel<<<N_ROWS / 4, 256, 0, stream>>>(
            residual, rin, cb, part, qout, idx_out, s);
    }
}

// Round 4
// 3363.213 us; speedup vs baseline: 1.5646x; 1.5646x over previous
//
#include <hip/hip_runtime.h>
#include <math.h>

// Residual VQ, 4 stages, N=16384 rows, D=512, K=4096.
// Round 4: same bit-exact fp32 math as round 3 (PASSED, absmax=0), restructured
// for FMA-pipe saturation: 128x128 tile, 8x8 register blocking, d-major LDS
// with ds_read_b128 fragments (4 DS reads + 64 FMA per thread per d).
// Chain order per output preserved: fmaf over d = 0..511 ascending.

namespace {
constexpr int N_ROWS     = 16384;
constexpr int DIM        = 512;
constexpr int K_CODES    = 4096;
constexpr int NUM_STAGES = 4;

constexpr int TM = 128;               // rows per block
constexpr int TK = 128;               // codes per block
constexpr int DC = 16;                // d-chunk
constexpr int MTILES = N_ROWS / TM;   // 128
constexpr int KTILES = K_CODES / TK;  // 32
constexpr int LSTR = TM + 4;          // 132 dwords: +4 bank rotation/d, 16B-aligned

// d_out layout (all read back as float32):
constexpr size_t Q_OFF    = 0;
constexpr size_t IDX_OFF  = (size_t)N_ROWS * DIM;                  // 8388608
constexpr size_t LOSS_OFF = IDX_OFF + (size_t)N_ROWS * NUM_STAGES; // 8454144

// ws layout (bytes):
constexpr size_t RES_OFF  = 0;                                   // 32 MB
constexpr size_t CBSQ_OFF = (size_t)N_ROWS * DIM * 4;            // +16 KB
constexpr size_t RSQ_OFF  = CBSQ_OFF + (size_t)K_CODES * 4;      // +64 KB
constexpr size_t PART_OFF = RSQ_OFF + (size_t)N_ROWS * 4;        // +4 MB

struct Partial { float val; int idx; };
} // namespace

// numpy pairwise sum-of-squares of a 512-float row, AVX512 base-case order.
// Valid result on lane 0 of each wave.
__device__ __forceinline__ float rowsq_pairwise(const float* __restrict__ row,
                                                int lane) {
#pragma clang fp contract(off)
    float P[4];
#pragma unroll
    for (int b = 0; b < 4; ++b) {
        float xa = row[b * 128 + lane];
        float xb = row[b * 128 + 64 + lane];
        float sa = xa * xa;
        float sb = xb * xb;
        float R  = sa + sb;
        float t  = R + __shfl_down(R, 16, 64);
        float u  = t + __shfl_down(t, 32, 64);
        float a  = u + __shfl_down(u, 8, 64);
        float c  = a + __shfl_down(a, 4, 64);
        float d  = c + __shfl_down(c, 2, 64);
        P[b]     = d + __shfl_down(d, 1, 64);
    }
    float s01 = P[0] + P[1];
    float s23 = P[2] + P[3];
    return s01 + s23;
}

__global__ __launch_bounds__(64)
void cbsq_kernel(const float* __restrict__ cb, float* __restrict__ cb_sq,
                 float* __restrict__ loss) {
    int k = blockIdx.x;
    int lane = threadIdx.x;
    float s = rowsq_pairwise(cb + (size_t)k * DIM, lane);
    if (lane == 0) cb_sq[k] = s;
    if (k == 0 && lane == 0) *loss = 0.0f;
}

__global__ __launch_bounds__(256)
void rsq_kernel(const float* __restrict__ res, float* __restrict__ rsq) {
    int lane = threadIdx.x & 63;
    int sub  = threadIdx.x >> 6;
    int row  = blockIdx.x * 4 + sub;
    float s = rowsq_pairwise(res + (size_t)row * DIM, lane);
    if (lane == 0) rsq[row] = s;
}

// 128x128 tile, 8x8 per-thread blocking, d-major LDS, b128 fragment reads.
__global__ __launch_bounds__(256)
void dist_argmin_kernel(const float* __restrict__ res,
                        const float* __restrict__ cb,
                        const float* __restrict__ cb_sq,
                        const float* __restrict__ rsq,
                        Partial* __restrict__ part) {
    const int kb = blockIdx.x;   // fast dim: consecutive blocks share A-panel
    const int mb = blockIdx.y;

    __shared__ __align__(16) float As[DC][LSTR];
    __shared__ __align__(16) float Bs[DC][LSTR];
    __shared__ float bval[TM][17];
    __shared__ int   bidx[TM][17];

    const int t  = threadIdx.x;
    const int tx = t & 15;
    const int ty = t >> 4;

    float acc[8][8];
#pragma unroll
    for (int i = 0; i < 8; ++i)
#pragma unroll
        for (int j = 0; j < 8; ++j) acc[i][j] = 0.0f;

    const float* aBase = res + (size_t)mb * TM * DIM;
    const float* bBase = cb  + (size_t)kb * TK * DIM;

    // Staging assignment: 512 float4 per operand per chunk; 2 per thread.
    const int srow = t >> 2;     // 0..63  (+64 for second half)
    const int sd4 = t & 3;       // which float4 along d (DC=16 -> 4 groups)

    float4 aReg[2], bReg[2];
#pragma unroll
    for (int l = 0; l < 2; ++l) {
        aReg[l] = *reinterpret_cast<const float4*>(aBase + (size_t)(srow + 64 * l) * DIM + 4 * sd4);
        bReg[l] = *reinterpret_cast<const float4*>(bBase + (size_t)(srow + 64 * l) * DIM + 4 * sd4);
    }

    for (int c = 0; c < DIM / DC; ++c) {
        // Transpose-write staged regs: d-major LDS.
#pragma unroll
        for (int l = 0; l < 2; ++l) {
            int r = srow + 64 * l;
            As[sd4 * 4 + 0][r] = aReg[l].x;
            As[sd4 * 4 + 1][r] = aReg[l].y;
            As[sd4 * 4 + 2][r] = aReg[l].z;
            As[sd4 * 4 + 3][r] = aReg[l].w;
            Bs[sd4 * 4 + 0][r] = bReg[l].x;
            Bs[sd4 * 4 + 1][r] = bReg[l].y;
            Bs[sd4 * 4 + 2][r] = bReg[l].z;
            Bs[sd4 * 4 + 3][r] = bReg[l].w;
        }
        __syncthreads();

        // Issue next chunk's global loads early; they retire during compute.
        if (c + 1 < DIM / DC) {
            int dg = (c + 1) * DC + 4 * sd4;
#pragma unroll
            for (int l = 0; l < 2; ++l) {
                aReg[l] = *reinterpret_cast<const float4*>(aBase + (size_t)(srow + 64 * l) * DIM + dg);
                bReg[l] = *reinterpret_cast<const float4*>(bBase + (size_t)(srow + 64 * l) * DIM + dg);
            }
        }

        // Compute DC d-steps; per d: 4 ds_read_b128 + 64 fmaf.
        // Chain order per acc[i][j] is d ascending -> bit-exact.
#pragma unroll
        for (int d = 0; d < DC; ++d) {
            float4 a0 = *reinterpret_cast<const float4*>(&As[d][ty * 4]);
            float4 a1 = *reinterpret_cast<const float4*>(&As[d][64 + ty * 4]);
            float4 b0 = *reinterpret_cast<const float4*>(&Bs[d][tx * 4]);
            float4 b1 = *reinterpret_cast<const float4*>(&Bs[d][64 + tx * 4]);
            float av[8] = {a0.x, a0.y, a0.z, a0.w, a1.x, a1.y, a1.z, a1.w};
            float bv[8] = {b0.x, b0.y, b0.z, b0.w, b1.x, b1.y, b1.z, b1.w};
#pragma unroll
            for (int i = 0; i < 8; ++i)
#pragma unroll
                for (int j = 0; j < 8; ++j)
                    acc[i][j] = fmaf(av[i], bv[j], acc[i][j]);
        }
        __syncthreads();
    }

    // Distances + per-thread argmin per row (candidate k ascending per thread).
    const int rbase = mb * TM;
    const int cbase = kb * TK;
#pragma unroll
    for (int i = 0; i < 8; ++i) {
        int rloc = (i < 4) ? (ty * 4 + i) : (64 + ty * 4 + (i - 4));
        float rsqv = rsq[rbase + rloc];
        float bv = INFINITY; int bi = 0x7fffffff;
#pragma unroll
        for (int j = 0; j < 8; ++j) {
            int cloc = (j < 4) ? (tx * 4 + j) : (64 + tx * 4 + (j - 4));
            int kg = cbase + cloc;
            float y;
            {
#pragma clang fp contract(off)
                float t2 = 2.0f * acc[i][j];
                float u  = rsqv - t2;
                y        = u + cb_sq[kg];
            }
            if (y < bv || (y == bv && kg < bi)) { bv = y; bi = kg; }
        }
        bval[rloc][tx] = bv;
        bidx[rloc][tx] = bi;
    }
    __syncthreads();

    if (t < TM) {
        float bv = bval[t][0]; int bi = bidx[t][0];
#pragma unroll
        for (int x = 1; x < 16; ++x) {
            float v = bval[t][x]; int ix = bidx[t][x];
            if (v < bv || (v == bv && ix < bi)) { bv = v; bi = ix; }
        }
        Partial p; p.val = bv; p.idx = bi;
        part[(size_t)(rbase + t) * KTILES + kb] = p;
    }
}

// Reduce partials; write index (as float), exact fp32 residual/q_ste update.
__global__ __launch_bounds__(256)
void combine_kernel(float* __restrict__ res_out,
                    const float* __restrict__ res_in,
                    const float* __restrict__ cb,
                    const Partial* __restrict__ part,
                    float* __restrict__ qout,
                    float* __restrict__ idx_out,
                    int stage) {
#pragma clang fp contract(off)
    const int t    = threadIdx.x;
    const int lane = t & 63;
    const int sub  = t >> 6;
    const int row  = blockIdx.x * 4 + sub;

    Partial p = part[(size_t)row * KTILES + (lane & 31)];
    float bv = p.val; int bi = p.idx;
#pragma unroll
    for (int off = 16; off > 0; off >>= 1) {
        float ov = __shfl_down(bv, off, 64);
        int   oi = __shfl_down(bi, off, 64);
        if (ov < bv || (ov == bv && oi < bi)) { bv = ov; bi = oi; }
    }
    bi = __shfl(bi, 0, 64);

    if (lane == 0) idx_out[(size_t)row * NUM_STAGES + stage] = (float)bi;

    const float* w   = cb + (size_t)bi * DIM;
    const float* rin = res_in + (size_t)row * DIM;
    float*       r   = res_out + (size_t)row * DIM;
    float*       q   = qout + (size_t)row * DIM;
#pragma unroll
    for (int i = 0; i < DIM / 64; ++i) {
        int d = lane + i * 64;
        float wv = w[d];
        float rv = rin[d];
        float tq    = wv - rv;     // fl(q - r)
        float q_ste = rv + tq;     // fl(r + (q - r))
        float rn    = rv - q_ste;  // fl(r - q_ste)
        r[d] = rn;
        if (stage == 0) q[d] = q_ste;
        else            q[d] = q[d] + q_ste;   // stage-order fp32 accumulation
    }
}

extern "C" void kernel_launch(void* const* d_in, const int* in_sizes, int n_in,
                              void* d_out, int out_size, void* d_ws, size_t ws_size,
                              hipStream_t stream) {
    const float* input = (const float*)d_in[0];
    const float* cb    = (const float*)d_in[1];

    float* out_f   = (float*)d_out;
    float* qout    = out_f + Q_OFF;
    float* idx_out = out_f + IDX_OFF;
    float* loss    = out_f + LOSS_OFF;

    char* ws = (char*)d_ws;
    float*   residual = (float*)(ws + RES_OFF);
    float*   cb_sq    = (float*)(ws + CBSQ_OFF);
    float*   rsq      = (float*)(ws + RSQ_OFF);
    Partial* part     = (Partial*)(ws + PART_OFF);

    cbsq_kernel<<<K_CODES, 64, 0, stream>>>(cb, cb_sq, loss);

    for (int s = 0; s < NUM_STAGES; ++s) {
        const float* rin = (s == 0) ? input : residual;
        rsq_kernel<<<N_ROWS / 4, 256, 0, stream>>>(rin, rsq);
        dist_argmin_kernel<<<dim3(KTILES, MTILES), 256, 0, stream>>>(
            rin, cb, cb_sq, rsq, part);
        combine_kernel<<<N_ROWS / 4, 256, 0, stream>>>(
            residual, rin, cb, part, qout, idx_out, s);
    }
}